// Round 1
// 402.217 us; speedup vs baseline: 1.1022x; 1.1022x over previous
//
#include <hip/hip_runtime.h>

// Fully-fused MLP, Round 4: wave-independent full-weight-in-register design.
//
// Each wave holds the ENTIRE weight set as MFMA A-frags (38 frags = 152 VGPR)
// and pushes 16 batch rows per iteration through all 6 layers on its own:
//   - no __syncthreads anywhere (per-wave private LDS; in-wave DS ops are
//     in-order, compiler inserts lgkmcnt only for read-result uses)
//   - per-layer LDS transpose: 4x ds_write_b64 + 2x ds_read_b128 (vs 4+8
//     per wave in the 4-wave feature-split) into a padded [row][feat] tile,
//     row stride 144 B -> conflict-optimal writes (4cy) and b128 reads (8cy)
//   - v_cvt_pk_bf16_f32 (1 instr / 2 floats) for every f32->bf16 pack
// Register image ~210-240 -> __launch_bounds__(256,2) -> 2 waves/SIMD.

typedef __attribute__((ext_vector_type(8))) short short8;   // 8 x bf16 frag
typedef __attribute__((ext_vector_type(4))) float f32x4;    // MFMA acc

#define BATCH   2097152
#define NBLOCKS 1024
#define WAVES   (NBLOCKS * 4)            // 4096 independent waves
#define ITERS   (BATCH / (WAVES * 16))   // 32 batches of 16 rows per wave
#define RSTRIDE 144                      // LDS bytes per row (128 + 16 pad)
#define BUFSZ   (16 * RSTRIDE)           // 2304 B per buffer
#define WREGION (2 * BUFSZ)              // 4608 B per wave (double buffer)
static_assert(BATCH == NBLOCKS * 4 * 16 * ITERS, "");

// packed f32x2 -> bf16x2, RNE, single instruction (no builtin on gfx950)
__device__ __forceinline__ unsigned cvt_pk(float a, float b) {
    unsigned r;
    asm("v_cvt_pk_bf16_f32 %0, %1, %2" : "=v"(r) : "v"(a), "v"(b));
    return r;
}

__global__ __launch_bounds__(256, 2)
void mlp_fused(const float* __restrict__ x, const float* __restrict__ W0,
               const float* __restrict__ Wh, const float* __restrict__ Wo,
               float* __restrict__ out)
{
    __shared__ __align__(16) unsigned char smem[4 * WREGION];  // 18432 B

    const int tid  = threadIdx.x;
    const int w    = tid >> 6;       // wave id within block (LDS region only)
    const int lane = tid & 63;
    const int n = lane & 15;         // A: m index / B: batch col / C: col
    const int q = lane >> 4;         // k-group (A,B) / row-group (C)

    // ---------------- weights: full set per wave, 38 frags -----------------
    // A-frag layout: A[m=lane&15][k=8q+j], value = W[k][16t+m]  (t = out tile)
    short8 wf0[4], wfh[4][4][2], wfo[2];
    #pragma unroll
    for (int t = 0; t < 4; ++t) {                       // W0 [32][64]
        const float* p = W0 + (8 * q) * 64 + 16 * t + n;
        union { unsigned u[4]; short8 s; } f;
        #pragma unroll
        for (int i = 0; i < 4; ++i)
            f.u[i] = cvt_pk(p[(2 * i) * 64], p[(2 * i + 1) * 64]);
        wf0[t] = f.s;
    }
    #pragma unroll
    for (int l = 0; l < 4; ++l)                         // Wh [4][64][64]
        #pragma unroll
        for (int t = 0; t < 4; ++t)
            #pragma unroll
            for (int c = 0; c < 2; ++c) {
                const float* p = Wh + l * 4096 + (32 * c + 8 * q) * 64 + 16 * t + n;
                union { unsigned u[4]; short8 s; } f;
                #pragma unroll
                for (int i = 0; i < 4; ++i)
                    f.u[i] = cvt_pk(p[(2 * i) * 64], p[(2 * i + 1) * 64]);
                wfh[l][t][c] = f.s;
            }
    #pragma unroll
    for (int c = 0; c < 2; ++c) {                       // Wo [64][3]
        union { unsigned u[4]; short8 s; } f;
        #pragma unroll
        for (int i = 0; i < 4; ++i) {
            float a = (n < 3) ? Wo[(32 * c + 8 * q + 2 * i)     * 3 + n] : 0.f;
            float b = (n < 3) ? Wo[(32 * c + 8 * q + 2 * i + 1) * 3 + n] : 0.f;
            f.u[i] = cvt_pk(a, b);
        }
        wfo[c] = f.s;
    }

    // ---------------- per-wave LDS byte offsets ----------------------------
    // [row n][feat] bf16, row stride 144 B. write unit = 8B (feats 16t+4q..+3)
    // at byte 32t+8q; read unit = 16B (feats 64c/2.. = 32c+8q..+7) at 64c+16q.
    unsigned char* const smw = smem + w * WREGION;
    const unsigned aw = (unsigned)n * RSTRIDE + 8u  * (unsigned)q;
    const unsigned ar = (unsigned)n * RSTRIDE + 16u * (unsigned)q;

    const int gw = blockIdx.x * 4 + w;
    const f32x4 z = {0.f, 0.f, 0.f, 0.f};

    // x B-frag for batch 0: b[n][k=8q+j] = x[row0+n][8q+j]
    short8 xfn;
    {
        const f32x4* xp = (const f32x4*)(x + ((size_t)gw * 16 + n) * 32) + 2 * q;
        f32x4 a = xp[0], b = xp[1];
        union { unsigned u[4]; short8 s; } f;
        f.u[0] = cvt_pk(a[0], a[1]); f.u[1] = cvt_pk(a[2], a[3]);
        f.u[2] = cvt_pk(b[0], b[1]); f.u[3] = cvt_pk(b[2], b[3]);
        xfn = f.s;
    }

    #pragma unroll 1
    for (int it = 0; it < ITERS; ++it) {
        const short8 xf   = xfn;
        const size_t row0 = ((size_t)it * WAVES + gw) * 16;

        // L0: 4 output tiles from the x frag (K=32, one B-frag)
        f32x4 acc[4];
        #pragma unroll
        for (int t = 0; t < 4; ++t)
            acc[t] = __builtin_amdgcn_mfma_f32_16x16x32_bf16(wf0[t], xf, z, 0, 0, 0);

        // prefetch + convert next batch's x (5 layers of latency to cover)
        if (it + 1 < ITERS) {
            const size_t r1 = ((size_t)(it + 1) * WAVES + gw) * 16;
            const f32x4* xp = (const f32x4*)(x + (r1 + n) * 32) + 2 * q;
            f32x4 a = xp[0], b = xp[1];
            union { unsigned u[4]; short8 s; } f;
            f.u[0] = cvt_pk(a[0], a[1]); f.u[1] = cvt_pk(a[2], a[3]);
            f.u[2] = cvt_pk(b[0], b[1]); f.u[3] = cvt_pk(b[2], b[3]);
            xfn = f.s;
        }

        #pragma unroll
        for (int s = 0; s < 5; ++s) {
            // buffer parity rotates with batch so batch i+1's first write
            // never lands on the buffer batch i's output stage just read
            unsigned char* buf = smw + (((unsigned)(s + it) & 1u) * BUFSZ);

            // pack+write tiles 0,1 -> read b0 (needs only feats 0..31) ->
            // pack+write tiles 2,3 -> read b1. In-wave DS is in-order, so
            // b0's MFMAs can start while tiles 2,3 still drain.
            #pragma unroll
            for (int t = 0; t < 2; ++t) {
                uint2 wv;
                wv.x = cvt_pk(fmaxf(acc[t][0], 0.f), fmaxf(acc[t][1], 0.f));
                wv.y = cvt_pk(fmaxf(acc[t][2], 0.f), fmaxf(acc[t][3], 0.f));
                *(uint2*)(buf + aw + 32u * t) = wv;               // ds_write_b64
            }
            short8 b0 = *(const short8*)(buf + ar);               // ds_read_b128
            #pragma unroll
            for (int t = 2; t < 4; ++t) {
                uint2 wv;
                wv.x = cvt_pk(fmaxf(acc[t][0], 0.f), fmaxf(acc[t][1], 0.f));
                wv.y = cvt_pk(fmaxf(acc[t][2], 0.f), fmaxf(acc[t][3], 0.f));
                *(uint2*)(buf + aw + 32u * t) = wv;
            }
            short8 b1 = *(const short8*)(buf + ar + 64u);

            if (s < 4) {
                #pragma unroll
                for (int t = 0; t < 4; ++t)
                    acc[t] = __builtin_amdgcn_mfma_f32_16x16x32_bf16(
                                 wfh[s][t][0], b0, z, 0, 0, 0);
                #pragma unroll
                for (int t = 0; t < 4; ++t)
                    acc[t] = __builtin_amdgcn_mfma_f32_16x16x32_bf16(
                                 wfh[s][t][1], b1, acc[t], 0, 0, 0);
            } else {
                // output layer: C rows 0..2 (q=0 regs) = out feats, col = batch
                f32x4 o = __builtin_amdgcn_mfma_f32_16x16x32_bf16(wfo[0], b0, z, 0, 0, 0);
                o = __builtin_amdgcn_mfma_f32_16x16x32_bf16(wfo[1], b1, o, 0, 0, 0);
                if (lane < 16) {
                    float* po = out + (row0 + lane) * 3;
                    po[0] = o[0]; po[1] = o[1]; po[2] = o[2];
                }
            }
        }
    }
}

extern "C" void kernel_launch(void* const* d_in, const int* in_sizes, int n_in,
                              void* d_out, int out_size, void* d_ws, size_t ws_size,
                              hipStream_t stream) {
    (void)in_sizes; (void)n_in; (void)d_ws; (void)ws_size; (void)out_size;
    const float* x  = (const float*)d_in[0];
    const float* W0 = (const float*)d_in[1];
    const float* Wh = (const float*)d_in[2];
    const float* Wo = (const float*)d_in[3];
    float* out = (float*)d_out;
    mlp_fused<<<NBLOCKS, 256, 0, stream>>>(x, W0, Wh, Wo, out);
}

// Round 2
// 386.015 us; speedup vs baseline: 1.1484x; 1.0420x over previous
//
#include <hip/hip_runtime.h>

// Fully-fused MLP, Round 5: wave-independent + DUAL-STREAM per wave.
//
// Each wave holds the ENTIRE weight set as MFMA A-frags (38 frags = 152 VGPR)
// and pushes TWO independent 16-row batches per iteration through all 6
// layers, interleaved per layer. Stream B's pack/DS/MFMA work hides stream
// A's per-layer LDS round-trip latency (ds_write -> in-order ds_read ~120cy)
// and vice versa -> 4 independent dependency chains per SIMD at 2 waves/SIMD.
//
//   - no __syncthreads anywhere; per-wave private LDS, single buffer per
//     stream (in-wave DS ops are in-order -> write-after-read is safe)
//   - next-iter x loaded as raw f32 a FULL iteration ahead (vmcnt distance
//     ~1500cy >> 900cy HBM latency), converted at the top of the next iter
//   - v_cvt_pk_bf16_f32 for every f32->bf16 pack
//   - LDS row stride 144 B: conflict-optimal b64 writes / b128 reads
// Register image ~240 -> __launch_bounds__(256,2) -> 2 waves/SIMD.

typedef __attribute__((ext_vector_type(8))) short short8;   // 8 x bf16 frag
typedef __attribute__((ext_vector_type(4))) float f32x4;    // MFMA acc

#define BATCH   2097152
#define NBLOCKS 1024
#define WAVES   (NBLOCKS * 4)            // 4096 independent waves
#define ROWS_PW 32                       // 2 streams x 16 rows per iteration
#define ITERS   (BATCH / (WAVES * ROWS_PW))   // 16
#define RSTRIDE 144                      // LDS bytes per row (128 + 16 pad)
#define BUFSZ   (16 * RSTRIDE)           // 2304 B per stream buffer
static_assert(BATCH == (size_t)WAVES * ROWS_PW * ITERS, "");

// packed f32x2 -> bf16x2, RNE, single instruction (no builtin on gfx950)
__device__ __forceinline__ unsigned cvt_pk(float a, float b) {
    unsigned r;
    asm("v_cvt_pk_bf16_f32 %0, %1, %2" : "=v"(r) : "v"(a), "v"(b));
    return r;
}

__global__ __launch_bounds__(256, 2)
void mlp_fused(const float* __restrict__ x, const float* __restrict__ W0,
               const float* __restrict__ Wh, const float* __restrict__ Wo,
               float* __restrict__ out)
{
    __shared__ __align__(16) unsigned char smem[4 * 2 * BUFSZ];  // 18432 B

    const int tid  = threadIdx.x;
    const int w    = tid >> 6;       // wave id within block (LDS region only)
    const int lane = tid & 63;
    const int n = lane & 15;         // A: m index / B: batch col / C: col
    const int q = lane >> 4;         // k-group (A,B) / row-group (C)

    // ---------------- weights: full set per wave, 38 frags -----------------
    // A-frag layout: A[m=lane&15][k=8q+j], value = W[k][16t+m]  (t = out tile)
    short8 wf0[4], wfh[4][4][2], wfo[2];
    #pragma unroll
    for (int t = 0; t < 4; ++t) {                       // W0 [32][64]
        const float* p = W0 + (8 * q) * 64 + 16 * t + n;
        union { unsigned u[4]; short8 s; } f;
        #pragma unroll
        for (int i = 0; i < 4; ++i)
            f.u[i] = cvt_pk(p[(2 * i) * 64], p[(2 * i + 1) * 64]);
        wf0[t] = f.s;
    }
    #pragma unroll
    for (int l = 0; l < 4; ++l)                         // Wh [4][64][64]
        #pragma unroll
        for (int t = 0; t < 4; ++t)
            #pragma unroll
            for (int c = 0; c < 2; ++c) {
                const float* p = Wh + l * 4096 + (32 * c + 8 * q) * 64 + 16 * t + n;
                union { unsigned u[4]; short8 s; } f;
                #pragma unroll
                for (int i = 0; i < 4; ++i)
                    f.u[i] = cvt_pk(p[(2 * i) * 64], p[(2 * i + 1) * 64]);
                wfh[l][t][c] = f.s;
            }
    #pragma unroll
    for (int c = 0; c < 2; ++c) {                       // Wo [64][3]
        union { unsigned u[4]; short8 s; } f;
        #pragma unroll
        for (int i = 0; i < 4; ++i) {
            float a = (n < 3) ? Wo[(32 * c + 8 * q + 2 * i)     * 3 + n] : 0.f;
            float b = (n < 3) ? Wo[(32 * c + 8 * q + 2 * i + 1) * 3 + n] : 0.f;
            f.u[i] = cvt_pk(a, b);
        }
        wfo[c] = f.s;
    }

    // ---------------- per-wave LDS byte offsets ----------------------------
    // [row n][feat] bf16, row stride 144 B. write unit = 8B (feats 16t+4q..+3)
    // at byte 32t+8q; read unit = 16B (feats 32c+8q..+7) at 64c+16q.
    unsigned char* const bufA = smem + w * (2 * BUFSZ);
    unsigned char* const bufB = bufA + BUFSZ;
    const unsigned aw = (unsigned)n * RSTRIDE + 8u  * (unsigned)q;
    const unsigned ar = (unsigned)n * RSTRIDE + 16u * (unsigned)q;

    const int gw = blockIdx.x * 4 + w;
    const f32x4 z = {0.f, 0.f, 0.f, 0.f};

    // raw next-iteration x (issued one full iteration ahead of the convert)
    f32x4 rawA[2], rawB[2];
    auto issue_x = [&](int it) {
        const size_t r = ((size_t)it * WAVES + gw) * ROWS_PW;
        const f32x4* pA = (const f32x4*)(x + (r + n) * 32) + 2 * q;
        rawA[0] = pA[0]; rawA[1] = pA[1];
        const f32x4* pB = (const f32x4*)(x + (r + 16 + n) * 32) + 2 * q;
        rawB[0] = pB[0]; rawB[1] = pB[1];
    };
    auto convert_x = [&](const f32x4* raw) -> short8 {
        union { unsigned u[4]; short8 s; } f;
        f.u[0] = cvt_pk(raw[0][0], raw[0][1]);
        f.u[1] = cvt_pk(raw[0][2], raw[0][3]);
        f.u[2] = cvt_pk(raw[1][0], raw[1][1]);
        f.u[3] = cvt_pk(raw[1][2], raw[1][3]);
        return f.s;
    };
    // pack+write one stream's activations, read back next layer's B-frags
    auto stage = [&](const f32x4 (&acc)[4], unsigned char* buf,
                     short8& b0, short8& b1) {
        #pragma unroll
        for (int t = 0; t < 4; ++t) {
            uint2 wv;
            wv.x = cvt_pk(fmaxf(acc[t][0], 0.f), fmaxf(acc[t][1], 0.f));
            wv.y = cvt_pk(fmaxf(acc[t][2], 0.f), fmaxf(acc[t][3], 0.f));
            *(uint2*)(buf + aw + 32u * t) = wv;          // ds_write_b64
        }
        b0 = *(const short8*)(buf + ar);                 // ds_read_b128
        b1 = *(const short8*)(buf + ar + 64u);
    };

    issue_x(0);

    #pragma unroll 1
    for (int it = 0; it < ITERS; ++it) {
        // converts wait on loads issued a FULL iteration ago -> no stall
        const short8 xfA = convert_x(rawA);
        const short8 xfB = convert_x(rawB);
        if (it + 1 < ITERS) issue_x(it + 1);   // WAR on raw regs, in-order

        const size_t row0 = ((size_t)it * WAVES + gw) * ROWS_PW;

        // L0: both streams (8 independent MFMAs)
        f32x4 accA[4], accB[4];
        #pragma unroll
        for (int t = 0; t < 4; ++t)
            accA[t] = __builtin_amdgcn_mfma_f32_16x16x32_bf16(wf0[t], xfA, z, 0, 0, 0);
        #pragma unroll
        for (int t = 0; t < 4; ++t)
            accB[t] = __builtin_amdgcn_mfma_f32_16x16x32_bf16(wf0[t], xfB, z, 0, 0, 0);

        // hidden layers: interleave streams so B's work hides A's LDS latency
        #pragma unroll
        for (int s = 0; s < 4; ++s) {
            short8 a0, a1, c0, c1;
            stage(accA, bufA, a0, a1);
            stage(accB, bufB, c0, c1);
            #pragma unroll
            for (int t = 0; t < 4; ++t)
                accA[t] = __builtin_amdgcn_mfma_f32_16x16x32_bf16(
                              wfh[s][t][0], a0, z, 0, 0, 0);
            #pragma unroll
            for (int t = 0; t < 4; ++t)
                accA[t] = __builtin_amdgcn_mfma_f32_16x16x32_bf16(
                              wfh[s][t][1], a1, accA[t], 0, 0, 0);
            #pragma unroll
            for (int t = 0; t < 4; ++t)
                accB[t] = __builtin_amdgcn_mfma_f32_16x16x32_bf16(
                              wfh[s][t][0], c0, z, 0, 0, 0);
            #pragma unroll
            for (int t = 0; t < 4; ++t)
                accB[t] = __builtin_amdgcn_mfma_f32_16x16x32_bf16(
                              wfh[s][t][1], c1, accB[t], 0, 0, 0);
        }

        // output layer: C rows 0..2 (q=0 regs) = out feats, col = batch
        {
            short8 a0, a1, c0, c1;
            stage(accA, bufA, a0, a1);
            stage(accB, bufB, c0, c1);
            f32x4 oA = __builtin_amdgcn_mfma_f32_16x16x32_bf16(wfo[0], a0, z, 0, 0, 0);
            oA = __builtin_amdgcn_mfma_f32_16x16x32_bf16(wfo[1], a1, oA, 0, 0, 0);
            f32x4 oB = __builtin_amdgcn_mfma_f32_16x16x32_bf16(wfo[0], c0, z, 0, 0, 0);
            oB = __builtin_amdgcn_mfma_f32_16x16x32_bf16(wfo[1], c1, oB, 0, 0, 0);
            if (lane < 16) {
                float* pA = out + (row0 + lane) * 3;
                pA[0] = oA[0]; pA[1] = oA[1]; pA[2] = oA[2];
                float* pB = out + (row0 + 16 + lane) * 3;
                pB[0] = oB[0]; pB[1] = oB[1]; pB[2] = oB[2];
            }
        }
    }
}

extern "C" void kernel_launch(void* const* d_in, const int* in_sizes, int n_in,
                              void* d_out, int out_size, void* d_ws, size_t ws_size,
                              hipStream_t stream) {
    (void)in_sizes; (void)n_in; (void)d_ws; (void)ws_size; (void)out_size;
    const float* x  = (const float*)d_in[0];
    const float* W0 = (const float*)d_in[1];
    const float* Wh = (const float*)d_in[2];
    const float* Wo = (const float*)d_in[3];
    float* out = (float*)d_out;
    mlp_fused<<<NBLOCKS, 256, 0, stream>>>(x, W0, Wh, Wo, out);
}

// Round 3
// 383.152 us; speedup vs baseline: 1.1570x; 1.0075x over previous
//
#include <hip/hip_runtime.h>

// Fully-fused MLP, Round 6: ZERO-LDS — the layer-to-layer transpose is
// absorbed into the weight fragment layout.
//
// MFMA C-layout: lane n+16q' holds (feat 4q'+r, batch n). B-layout needs
// lane n+16q to hold feats 8q+j. Solution: build weight tile t's A-frag
// with column mapping  phi_t(m) = 32*(t>>1) + 8*(m>>2) + 4*(t&1) + (m&3)
// (bijection on 0..63). Then acc[t][r] at lane n+16q' holds feat
// phi_t(4q'+r), and per lane the 16 acc values are exactly feats
// {8q'..8q'+7} (acc[0..1]) and {32+8q'..+7} (acc[2..3]) — i.e. the next
// layer's B-fragments with NO cross-lane movement:
//     b0 = [cvt_pk(acc[0]), cvt_pk(acc[1])],  b1 = [cvt_pk(acc[2..3])].
// Every hidden layer consumes true-k-ordered B and emits phi-ordered C,
// so the scheme telescopes; only weight LOAD ADDRESSES change (preamble).
//
//   - no LDS, no barriers, no ds ops, no lgkmcnt in the loop at all
//   - dual independent 16-row streams per wave (4 chains / SIMD @ 2 waves)
//   - next-iter x loaded raw a full iteration ahead (~1000cy vmcnt distance)
// Register image ~235 -> __launch_bounds__(256,2) -> 2 waves/SIMD.

typedef __attribute__((ext_vector_type(8))) short short8;   // 8 x bf16 frag
typedef __attribute__((ext_vector_type(4))) float f32x4;    // MFMA acc

#define BATCH   2097152
#define NBLOCKS 1024
#define WAVES   (NBLOCKS * 4)                 // 4096 independent waves
#define ROWS_PW 32                            // 2 streams x 16 rows / iter
#define ITERS   (BATCH / (WAVES * ROWS_PW))   // 16
static_assert(BATCH == (size_t)WAVES * ROWS_PW * ITERS, "");

// packed f32x2 -> bf16x2, RNE, single instruction (no builtin on gfx950)
__device__ __forceinline__ unsigned cvt_pk(float a, float b) {
    unsigned r;
    asm("v_cvt_pk_bf16_f32 %0, %1, %2" : "=v"(r) : "v"(a), "v"(b));
    return r;
}

__global__ __launch_bounds__(256, 2)
void mlp_fused(const float* __restrict__ x, const float* __restrict__ W0,
               const float* __restrict__ Wh, const float* __restrict__ Wo,
               float* __restrict__ out)
{
    const int tid  = threadIdx.x;
    const int w    = tid >> 6;       // wave id within block
    const int lane = tid & 63;
    const int n = lane & 15;         // A: m index / B: batch col / C: col
    const int q = lane >> 4;         // k-group (A,B) / row-group (C)

    // phi_t(n): weight column for tile t held at A-frag m-index n
    int phi[4];
    #pragma unroll
    for (int t = 0; t < 4; ++t)
        phi[t] = 32 * (t >> 1) + 8 * (n >> 2) + 4 * (t & 1) + (n & 3);

    // ---------------- weights: full set per wave, 38 frags -----------------
    // A-frag: A[m=lane&15][k=8q+j] = W[k][phi_t(m)]  (Wo: standard columns)
    short8 wf0[4], wfh[4][4][2], wfo[2];
    #pragma unroll
    for (int t = 0; t < 4; ++t) {                       // W0 [32][64]
        const float* p = W0 + (8 * q) * 64 + phi[t];
        union { unsigned u[4]; short8 s; } f;
        #pragma unroll
        for (int i = 0; i < 4; ++i)
            f.u[i] = cvt_pk(p[(2 * i) * 64], p[(2 * i + 1) * 64]);
        wf0[t] = f.s;
    }
    #pragma unroll
    for (int l = 0; l < 4; ++l)                         // Wh [4][64][64]
        #pragma unroll
        for (int t = 0; t < 4; ++t)
            #pragma unroll
            for (int c = 0; c < 2; ++c) {
                const float* p = Wh + l * 4096 + (32 * c + 8 * q) * 64 + phi[t];
                union { unsigned u[4]; short8 s; } f;
                #pragma unroll
                for (int i = 0; i < 4; ++i)
                    f.u[i] = cvt_pk(p[(2 * i) * 64], p[(2 * i + 1) * 64]);
                wfh[l][t][c] = f.s;
            }
    #pragma unroll
    for (int c = 0; c < 2; ++c) {                       // Wo [64][3]
        union { unsigned u[4]; short8 s; } f;
        #pragma unroll
        for (int i = 0; i < 4; ++i) {
            float a = (n < 3) ? Wo[(32 * c + 8 * q + 2 * i)     * 3 + n] : 0.f;
            float b = (n < 3) ? Wo[(32 * c + 8 * q + 2 * i + 1) * 3 + n] : 0.f;
            f.u[i] = cvt_pk(a, b);
        }
        wfo[c] = f.s;
    }

    const int gw = blockIdx.x * 4 + w;
    const f32x4 z = {0.f, 0.f, 0.f, 0.f};

    // raw next-iteration x (issued one full iteration ahead of the convert)
    f32x4 rawA[2], rawB[2];
    auto issue_x = [&](int it) {
        const size_t r = ((size_t)it * WAVES + gw) * ROWS_PW;
        const f32x4* pA = (const f32x4*)(x + (r + n) * 32) + 2 * q;
        rawA[0] = pA[0]; rawA[1] = pA[1];
        const f32x4* pB = (const f32x4*)(x + (r + 16 + n) * 32) + 2 * q;
        rawB[0] = pB[0]; rawB[1] = pB[1];
    };
    auto convert_x = [&](const f32x4* raw) -> short8 {
        union { unsigned u[4]; short8 s; } f;
        f.u[0] = cvt_pk(raw[0][0], raw[0][1]);
        f.u[1] = cvt_pk(raw[0][2], raw[0][3]);
        f.u[2] = cvt_pk(raw[1][0], raw[1][1]);
        f.u[3] = cvt_pk(raw[1][2], raw[1][3]);
        return f.s;
    };
    // ReLU + pack acc -> next layer's B-frags, pure in-register (see header)
    auto packact = [&](const f32x4 (&acc)[4], short8& b0, short8& b1) {
        union { unsigned u[4]; short8 s; } A, B;
        A.u[0] = cvt_pk(fmaxf(acc[0][0], 0.f), fmaxf(acc[0][1], 0.f));
        A.u[1] = cvt_pk(fmaxf(acc[0][2], 0.f), fmaxf(acc[0][3], 0.f));
        A.u[2] = cvt_pk(fmaxf(acc[1][0], 0.f), fmaxf(acc[1][1], 0.f));
        A.u[3] = cvt_pk(fmaxf(acc[1][2], 0.f), fmaxf(acc[1][3], 0.f));
        B.u[0] = cvt_pk(fmaxf(acc[2][0], 0.f), fmaxf(acc[2][1], 0.f));
        B.u[1] = cvt_pk(fmaxf(acc[2][2], 0.f), fmaxf(acc[2][3], 0.f));
        B.u[2] = cvt_pk(fmaxf(acc[3][0], 0.f), fmaxf(acc[3][1], 0.f));
        B.u[3] = cvt_pk(fmaxf(acc[3][2], 0.f), fmaxf(acc[3][3], 0.f));
        b0 = A.s; b1 = B.s;
    };

    issue_x(0);

    #pragma unroll 1
    for (int it = 0; it < ITERS; ++it) {
        // converts wait on loads issued a FULL iteration ago -> no stall
        const short8 xfA = convert_x(rawA);
        const short8 xfB = convert_x(rawB);
        if (it + 1 < ITERS) issue_x(it + 1);   // WAR on raw regs, safe

        const size_t row0 = ((size_t)it * WAVES + gw) * ROWS_PW;

        // L0: both streams (8 independent MFMAs)
        f32x4 accA[4], accB[4];
        #pragma unroll
        for (int t = 0; t < 4; ++t)
            accA[t] = __builtin_amdgcn_mfma_f32_16x16x32_bf16(wf0[t], xfA, z, 0, 0, 0);
        #pragma unroll
        for (int t = 0; t < 4; ++t)
            accB[t] = __builtin_amdgcn_mfma_f32_16x16x32_bf16(wf0[t], xfB, z, 0, 0, 0);

        // hidden layers: pure register pipeline, streams interleaved
        #pragma unroll
        for (int s = 0; s < 4; ++s) {
            short8 a0, a1, c0, c1;
            packact(accA, a0, a1);
            packact(accB, c0, c1);
            #pragma unroll
            for (int t = 0; t < 4; ++t)
                accA[t] = __builtin_amdgcn_mfma_f32_16x16x32_bf16(
                              wfh[s][t][0], a0, z, 0, 0, 0);
            #pragma unroll
            for (int t = 0; t < 4; ++t)
                accA[t] = __builtin_amdgcn_mfma_f32_16x16x32_bf16(
                              wfh[s][t][1], a1, accA[t], 0, 0, 0);
            #pragma unroll
            for (int t = 0; t < 4; ++t)
                accB[t] = __builtin_amdgcn_mfma_f32_16x16x32_bf16(
                              wfh[s][t][0], c0, z, 0, 0, 0);
            #pragma unroll
            for (int t = 0; t < 4; ++t)
                accB[t] = __builtin_amdgcn_mfma_f32_16x16x32_bf16(
                              wfh[s][t][1], c1, accB[t], 0, 0, 0);
        }

        // output layer: C rows 0..2 (q'=0 regs) = out feats, col = batch
        {
            short8 a0, a1, c0, c1;
            packact(accA, a0, a1);
            packact(accB, c0, c1);
            f32x4 oA = __builtin_amdgcn_mfma_f32_16x16x32_bf16(wfo[0], a0, z, 0, 0, 0);
            oA = __builtin_amdgcn_mfma_f32_16x16x32_bf16(wfo[1], a1, oA, 0, 0, 0);
            f32x4 oB = __builtin_amdgcn_mfma_f32_16x16x32_bf16(wfo[0], c0, z, 0, 0, 0);
            oB = __builtin_amdgcn_mfma_f32_16x16x32_bf16(wfo[1], c1, oB, 0, 0, 0);
            if (lane < 16) {
                float* pA = out + (row0 + lane) * 3;
                pA[0] = oA[0]; pA[1] = oA[1]; pA[2] = oA[2];
                float* pB = out + (row0 + 16 + lane) * 3;
                pB[0] = oB[0]; pB[1] = oB[1]; pB[2] = oB[2];
            }
        }
    }
}

extern "C" void kernel_launch(void* const* d_in, const int* in_sizes, int n_in,
                              void* d_out, int out_size, void* d_ws, size_t ws_size,
                              hipStream_t stream) {
    (void)in_sizes; (void)n_in; (void)d_ws; (void)ws_size; (void)out_size;
    const float* x  = (const float*)d_in[0];
    const float* W0 = (const float*)d_in[1];
    const float* Wh = (const float*)d_in[2];
    const float* Wo = (const float*)d_in[3];
    float* out = (float*)d_out;
    mlp_fused<<<NBLOCKS, 256, 0, stream>>>(x, W0, Wh, Wo, out);
}

// Round 4
// 377.367 us; speedup vs baseline: 1.1747x; 1.0153x over previous
//
#include <hip/hip_runtime.h>

// Fully-fused MLP, Round 7: zero-LDS datapath + WEIGHTS STREAMED FROM LDS
// to break the 128-VGPR occupancy wall (2 -> 4 waves/SIMD).
//
// Round-6's phi-telescope is kept verbatim: weight tile t uses column map
// phi_t(m) = 32*(t>>1) + 8*(m>>2) + 4*(t&1) + (m&3), so each layer's MFMA
// accumulators ARE the next layer's B-fragments after ReLU+cvt_pk — no
// cross-lane movement, no activation LDS, no barriers in the loop.
//
// New: the 38 weight A-frags (152 VGPR if resident) are built once per
// block into LDS (38 frags x 64 lanes x 16 B = 38 KB, frag-major so lane i
// reads byte 16*i -> conflict-free ds_read_b128) and streamed through two
// 8-frag register buffers X/Y on a 6-stage even-parity schedule:
//   stage:   L0(W0) Wh0  Wh1  Wh2  Wh3  Wo     (parity closes each iter)
//   compute:   X     Y    X    Y    X    Y
//   read next: Y     X    Y    X    Y    X[0..3](W0, next iter)
// Each stage issues the next chunk's reads BEFORE its MFMAs (~310 cy of
// issue hides the ~120 cy LDS latency; compiler inserts exact lgkmcnt).
//
// Register image ~115-125 -> __launch_bounds__(256,4) -> 4 waves/SIMD,
// 1024 blocks all resident (single generation, ITERS=32, one preamble).

typedef __attribute__((ext_vector_type(8))) short short8;   // 8 x bf16 frag
typedef __attribute__((ext_vector_type(4))) float f32x4;    // MFMA acc

#define BATCH   2097152
#define NBLOCKS 1024
#define NWAVES  (NBLOCKS * 4)                 // 4096 waves, all resident
#define ITERS   (BATCH / (NWAVES * 16))       // 32 x 16 rows per wave
static_assert(BATCH == (size_t)NWAVES * 16 * ITERS, "");

// packed f32x2 -> bf16x2, RNE, single instruction (no builtin on gfx950)
__device__ __forceinline__ unsigned cvt_pk(float a, float b) {
    unsigned r;
    asm("v_cvt_pk_bf16_f32 %0, %1, %2" : "=v"(r) : "v"(a), "v"(b));
    return r;
}

__global__ __launch_bounds__(256, 4)
void mlp_fused(const float* __restrict__ x, const float* __restrict__ W0,
               const float* __restrict__ Wh, const float* __restrict__ Wo,
               float* __restrict__ out)
{
    // frag-major weight store: frag f, lane l at wlds[f][l] (16 B units)
    // f: W0 t -> t | Wh l,t,c -> 4 + 8l + 2t + c | Wo c -> 36 + c
    __shared__ short8 wlds[38][64];

    const int tid  = threadIdx.x;
    const int w    = tid >> 6;
    const int lane = tid & 63;
    const int n = lane & 15;         // A: m index / B: batch col / C: col
    const int q = lane >> 4;         // k-group (A,B) / row-group (C)

    const int gw = blockIdx.x * 4 + w;

    // issue batch-0 x loads before the weight preamble (overlap HBM latency)
    f32x4 raw0, raw1;
    {
        const f32x4* p = (const f32x4*)(x + ((size_t)gw * 16 + n) * 32) + 2 * q;
        raw0 = p[0]; raw1 = p[1];
    }

    // phi_t(n): weight column for tile t held at A-frag m-index n
    int phi[4];
    #pragma unroll
    for (int t = 0; t < 4; ++t)
        phi[t] = 32 * (t >> 1) + 8 * (n >> 2) + 4 * (t & 1) + (n & 3);

    // ---- preamble: waves cooperatively build all frags into LDS ----------
    // frag content depends only on (n,q), identical across waves, so any
    // wave can produce any frag. w0: W0 + Wh3 + Wo; w1..3: Wh0..2.
    auto build = [&](const float* p) -> short8 {   // p = &W[k0][col], stride 64
        union { unsigned u[4]; short8 s; } f;
        #pragma unroll
        for (int i = 0; i < 4; ++i)
            f.u[i] = cvt_pk(p[(2 * i) * 64], p[(2 * i + 1) * 64]);
        return f.s;
    };
    if (w == 0) {
        #pragma unroll
        for (int t = 0; t < 4; ++t)                                  // W0 [32][64]
            wlds[t][lane] = build(W0 + (8 * q) * 64 + phi[t]);
        #pragma unroll
        for (int t = 0; t < 4; ++t)                                  // Wh layer 3
            #pragma unroll
            for (int c = 0; c < 2; ++c)
                wlds[28 + 2 * t + c][lane] =
                    build(Wh + 3 * 4096 + (32 * c + 8 * q) * 64 + phi[t]);
        #pragma unroll
        for (int c = 0; c < 2; ++c) {                                // Wo [64][3]
            union { unsigned u[4]; short8 s; } f;
            #pragma unroll
            for (int i = 0; i < 4; ++i) {
                float a = (n < 3) ? Wo[(32 * c + 8 * q + 2 * i)     * 3 + n] : 0.f;
                float b = (n < 3) ? Wo[(32 * c + 8 * q + 2 * i + 1) * 3 + n] : 0.f;
                f.u[i] = cvt_pk(a, b);
            }
            wlds[36 + c][lane] = f.s;
        }
    } else {
        const int l = w - 1;                                         // Wh 0..2
        #pragma unroll
        for (int t = 0; t < 4; ++t)
            #pragma unroll
            for (int c = 0; c < 2; ++c)
                wlds[4 + 8 * l + 2 * t + c][lane] =
                    build(Wh + l * 4096 + (32 * c + 8 * q) * 64 + phi[t]);
    }
    __syncthreads();

    const f32x4 z = {0.f, 0.f, 0.f, 0.f};
    short8 X[8], Y[8];

    // prime: X[0..3] = W0 frags
    #pragma unroll
    for (int j = 0; j < 4; ++j) X[j] = wlds[j][lane];

    // ReLU + pack acc -> next layer's B-frags, pure in-register
    auto packact = [&](const f32x4 (&acc)[4], short8& b0, short8& b1) {
        union { unsigned u[4]; short8 s; } A, B;
        A.u[0] = cvt_pk(fmaxf(acc[0][0], 0.f), fmaxf(acc[0][1], 0.f));
        A.u[1] = cvt_pk(fmaxf(acc[0][2], 0.f), fmaxf(acc[0][3], 0.f));
        A.u[2] = cvt_pk(fmaxf(acc[1][0], 0.f), fmaxf(acc[1][1], 0.f));
        A.u[3] = cvt_pk(fmaxf(acc[1][2], 0.f), fmaxf(acc[1][3], 0.f));
        B.u[0] = cvt_pk(fmaxf(acc[2][0], 0.f), fmaxf(acc[2][1], 0.f));
        B.u[1] = cvt_pk(fmaxf(acc[2][2], 0.f), fmaxf(acc[2][3], 0.f));
        B.u[2] = cvt_pk(fmaxf(acc[3][0], 0.f), fmaxf(acc[3][1], 0.f));
        B.u[3] = cvt_pk(fmaxf(acc[3][2], 0.f), fmaxf(acc[3][3], 0.f));
        b0 = A.s; b1 = B.s;
    };

    #pragma unroll 1
    for (int it = 0; it < ITERS; ++it) {
        // convert x (loads issued a full iteration ago -> vmcnt satisfied)
        short8 xf;
        {
            union { unsigned u[4]; short8 s; } f;
            f.u[0] = cvt_pk(raw0[0], raw0[1]); f.u[1] = cvt_pk(raw0[2], raw0[3]);
            f.u[2] = cvt_pk(raw1[0], raw1[1]); f.u[3] = cvt_pk(raw1[2], raw1[3]);
            xf = f.s;
        }
        if (it + 1 < ITERS) {
            const size_t r = ((size_t)(it + 1) * NWAVES + gw) * 16;
            const f32x4* p = (const f32x4*)(x + (r + n) * 32) + 2 * q;
            raw0 = p[0]; raw1 = p[1];
        }
        const size_t row0 = ((size_t)it * NWAVES + gw) * 16;

        f32x4 acc[4];
        short8 b0, b1;

        // S0: read Wh0 -> Y, compute L0 from X[0..3]
        #pragma unroll
        for (int j = 0; j < 8; ++j) Y[j] = wlds[4 + j][lane];
        #pragma unroll
        for (int t = 0; t < 4; ++t)
            acc[t] = __builtin_amdgcn_mfma_f32_16x16x32_bf16(X[t], xf, z, 0, 0, 0);

        // S1: read Wh1 -> X, compute Wh0 from Y
        #pragma unroll
        for (int j = 0; j < 8; ++j) X[j] = wlds[12 + j][lane];
        packact(acc, b0, b1);
        #pragma unroll
        for (int t = 0; t < 4; ++t)
            acc[t] = __builtin_amdgcn_mfma_f32_16x16x32_bf16(Y[2 * t], b0, z, 0, 0, 0);
        #pragma unroll
        for (int t = 0; t < 4; ++t)
            acc[t] = __builtin_amdgcn_mfma_f32_16x16x32_bf16(Y[2 * t + 1], b1, acc[t], 0, 0, 0);

        // S2: read Wh2 -> Y, compute Wh1 from X
        #pragma unroll
        for (int j = 0; j < 8; ++j) Y[j] = wlds[20 + j][lane];
        packact(acc, b0, b1);
        #pragma unroll
        for (int t = 0; t < 4; ++t)
            acc[t] = __builtin_amdgcn_mfma_f32_16x16x32_bf16(X[2 * t], b0, z, 0, 0, 0);
        #pragma unroll
        for (int t = 0; t < 4; ++t)
            acc[t] = __builtin_amdgcn_mfma_f32_16x16x32_bf16(X[2 * t + 1], b1, acc[t], 0, 0, 0);

        // S3: read Wh3 -> X, compute Wh2 from Y
        #pragma unroll
        for (int j = 0; j < 8; ++j) X[j] = wlds[28 + j][lane];
        packact(acc, b0, b1);
        #pragma unroll
        for (int t = 0; t < 4; ++t)
            acc[t] = __builtin_amdgcn_mfma_f32_16x16x32_bf16(Y[2 * t], b0, z, 0, 0, 0);
        #pragma unroll
        for (int t = 0; t < 4; ++t)
            acc[t] = __builtin_amdgcn_mfma_f32_16x16x32_bf16(Y[2 * t + 1], b1, acc[t], 0, 0, 0);

        // S4: read Wo -> Y[0..1], compute Wh3 from X
        Y[0] = wlds[36][lane];
        Y[1] = wlds[37][lane];
        packact(acc, b0, b1);
        #pragma unroll
        for (int t = 0; t < 4; ++t)
            acc[t] = __builtin_amdgcn_mfma_f32_16x16x32_bf16(X[2 * t], b0, z, 0, 0, 0);
        #pragma unroll
        for (int t = 0; t < 4; ++t)
            acc[t] = __builtin_amdgcn_mfma_f32_16x16x32_bf16(X[2 * t + 1], b1, acc[t], 0, 0, 0);

        // S5: read W0 -> X[0..3] (next iter), output layer from Y[0..1]
        #pragma unroll
        for (int j = 0; j < 4; ++j) X[j] = wlds[j][lane];
        packact(acc, b0, b1);
        f32x4 o = __builtin_amdgcn_mfma_f32_16x16x32_bf16(Y[0], b0, z, 0, 0, 0);
        o = __builtin_amdgcn_mfma_f32_16x16x32_bf16(Y[1], b1, o, 0, 0, 0);
        if (lane < 16) {
            float* po = out + (row0 + lane) * 3;
            po[0] = o[0]; po[1] = o[1]; po[2] = o[2];
        }
    }
}

extern "C" void kernel_launch(void* const* d_in, const int* in_sizes, int n_in,
                              void* d_out, int out_size, void* d_ws, size_t ws_size,
                              hipStream_t stream) {
    (void)in_sizes; (void)n_in; (void)d_ws; (void)ws_size; (void)out_size;
    const float* x  = (const float*)d_in[0];
    const float* W0 = (const float*)d_in[1];
    const float* Wh = (const float*)d_in[2];
    const float* Wo = (const float*)d_in[3];
    float* out = (float*)d_out;
    mlp_fused<<<NBLOCKS, 256, 0, stream>>>(x, W0, Wh, Wo, out);
}